// Round 1
// baseline (27255.988 us; speedup 1.0000x reference)
//
#include <hip/hip_runtime.h>
#include <hip/hip_bf16.h>
#include <stdint.h>
#include <math.h>

// Modern Hopfield retrieval: 11 passes of (sims -> online softmax -> PV) with
// per-step energy. B=1024 queries, N=65536 patterns, D=512, beta=1.
//
// Round 1: correctness-first f32 baseline (bf16 only for LDS-staged state).
// Structure mirrors the future MFMA version: flash-style partials per
// (qblock, N-chunk) + a combine kernel.

#define BQ    1024          // queries
#define DD    512           // dim
#define NP    65536         // patterns
#define NSTEP 10
#define QB    64            // queries per workgroup
#define NQB   (BQ / QB)     // 16
#define NCHK  16            // N chunks (split-N partials)
#define CN    (NP / NCHK)   // 4096 patterns per chunk
#define TN    32            // patterns per LDS tile
#define NTIL  (CN / TN)     // 128 tiles
#define SPAD  520           // bf16 elems per state row (pad 8)
#define PPAD  516           // f32 elems per pattern row (pad 4)

__device__ __forceinline__ unsigned short f2bf(float f) {
    uint32_t u = __float_as_uint(f);
    u += 0x7FFFu + ((u >> 16) & 1u);   // round-to-nearest-even
    return (unsigned short)(u >> 16);
}

__global__ __launch_bounds__(512) void hopf_pass(
    const float* __restrict__ patterns, const float* __restrict__ state,
    float* __restrict__ mpart, float* __restrict__ lpart,
    float* __restrict__ accp, int do_pv)
{
    __shared__ unsigned short Slds[QB * SPAD];  // 66560 B
    __shared__ float          Plds[TN * PPAD];  // 66048 B  (total ~132.6 KB)

    const int t    = threadIdx.x;
    const int lane = t & 63;
    const int g    = t & 15;          // lane within 16-lane group
    const int pair = t >> 4;          // 0..31 : owns query rows pair, pair+32
    const int chunk = blockIdx.x;     // 0..15
    const int qb0   = blockIdx.y * QB;
    const int q0l = pair, q1l = pair + 32;
    const int n0 = g, n1 = g + 16;    // this lane's pattern rows within a tile

    // ---- stage state block (f32 -> bf16) once ----
    for (int idx = t; idx < QB * DD; idx += 512) {
        const int r = idx >> 9, c = idx & (DD - 1);
        Slds[r * SPAD + c] = f2bf(state[(size_t)(qb0 + r) * DD + c]);
    }

    // per-thread accumulator: 2 query rows x 32 d columns (d = 4g + 64k + c)
    float acc0[32], acc1[32];
#pragma unroll
    for (int i = 0; i < 32; ++i) { acc0[i] = 0.f; acc1[i] = 0.f; }
    float m0 = -INFINITY, m1 = -INFINITY, l0 = 0.f, l1 = 0.f;

    const size_t pbase = (size_t)chunk * CN;

    for (int tile = 0; tile < NTIL; ++tile) {
        __syncthreads();   // previous PV / S-staging done before overwrite
        {
            const float* src = patterns + (pbase + (size_t)tile * TN) * DD;
            for (int idx = t; idx < TN * (DD / 4); idx += 512) {
                const int r = idx >> 7, c4 = (idx & 127) << 2;
                const float4 v = *reinterpret_cast<const float4*>(src + r * DD + c4);
                *reinterpret_cast<float4*>(&Plds[r * PPAD + c4]) = v;
            }
        }
        __syncthreads();

        // ---- sims: s[qsel][j] = dot(state[q], P[n_j]) ----
        float s00 = 0.f, s01 = 0.f, s10 = 0.f, s11 = 0.f;
        for (int dc = 0; dc < DD; dc += 8) {
            const uint4 ua = *reinterpret_cast<const uint4*>(&Slds[q0l * SPAD + dc]);
            const uint4 ub = *reinterpret_cast<const uint4*>(&Slds[q1l * SPAD + dc]);
            float fa[8], fb[8], pa[8], pb[8];
            fa[0] = __uint_as_float(ua.x << 16); fa[1] = __uint_as_float(ua.x & 0xFFFF0000u);
            fa[2] = __uint_as_float(ua.y << 16); fa[3] = __uint_as_float(ua.y & 0xFFFF0000u);
            fa[4] = __uint_as_float(ua.z << 16); fa[5] = __uint_as_float(ua.z & 0xFFFF0000u);
            fa[6] = __uint_as_float(ua.w << 16); fa[7] = __uint_as_float(ua.w & 0xFFFF0000u);
            fb[0] = __uint_as_float(ub.x << 16); fb[1] = __uint_as_float(ub.x & 0xFFFF0000u);
            fb[2] = __uint_as_float(ub.y << 16); fb[3] = __uint_as_float(ub.y & 0xFFFF0000u);
            fb[4] = __uint_as_float(ub.z << 16); fb[5] = __uint_as_float(ub.z & 0xFFFF0000u);
            fb[6] = __uint_as_float(ub.w << 16); fb[7] = __uint_as_float(ub.w & 0xFFFF0000u);
            *reinterpret_cast<float4*>(&pa[0]) = *reinterpret_cast<const float4*>(&Plds[n0 * PPAD + dc]);
            *reinterpret_cast<float4*>(&pa[4]) = *reinterpret_cast<const float4*>(&Plds[n0 * PPAD + dc + 4]);
            *reinterpret_cast<float4*>(&pb[0]) = *reinterpret_cast<const float4*>(&Plds[n1 * PPAD + dc]);
            *reinterpret_cast<float4*>(&pb[4]) = *reinterpret_cast<const float4*>(&Plds[n1 * PPAD + dc + 4]);
#pragma unroll
            for (int e = 0; e < 8; ++e) {
                s00 = fmaf(fa[e], pa[e], s00);
                s01 = fmaf(fa[e], pb[e], s01);
                s10 = fmaf(fb[e], pa[e], s10);
                s11 = fmaf(fb[e], pb[e], s11);
            }
        }

        // ---- online softmax update (per query row, over this 32-tile) ----
        float tm0 = fmaxf(s00, s01);
        float tm1 = fmaxf(s10, s11);
#pragma unroll
        for (int mk = 1; mk < 16; mk <<= 1) {
            tm0 = fmaxf(tm0, __shfl_xor(tm0, mk, 64));
            tm1 = fmaxf(tm1, __shfl_xor(tm1, mk, 64));
        }
        const float mn0 = fmaxf(m0, tm0), mn1 = fmaxf(m1, tm1);
        const float p00 = __expf(s00 - mn0), p01 = __expf(s01 - mn0);
        const float p10 = __expf(s10 - mn1), p11 = __expf(s11 - mn1);
        float sum0 = p00 + p01, sum1 = p10 + p11;
#pragma unroll
        for (int mk = 1; mk < 16; mk <<= 1) {
            sum0 += __shfl_xor(sum0, mk, 64);
            sum1 += __shfl_xor(sum1, mk, 64);
        }
        const float al0 = __expf(m0 - mn0), al1 = __expf(m1 - mn1);
        l0 = l0 * al0 + sum0;  l1 = l1 * al1 + sum1;
        m0 = mn0;  m1 = mn1;

        if (do_pv) {
#pragma unroll
            for (int i = 0; i < 32; ++i) { acc0[i] *= al0; acc1[i] *= al1; }
            const int base = lane & 48;
#pragma unroll 4
            for (int n = 0; n < TN; ++n) {
                const int src = base + (n & 15);
                const float w0 = __shfl((n < 16) ? p00 : p01, src, 64);
                const float w1 = __shfl((n < 16) ? p10 : p11, src, 64);
                const float* prow = &Plds[n * PPAD + 4 * g];
#pragma unroll
                for (int k = 0; k < 8; ++k) {
                    const float4 pv = *reinterpret_cast<const float4*>(prow + 64 * k);
                    acc0[4 * k + 0] = fmaf(w0, pv.x, acc0[4 * k + 0]);
                    acc0[4 * k + 1] = fmaf(w0, pv.y, acc0[4 * k + 1]);
                    acc0[4 * k + 2] = fmaf(w0, pv.z, acc0[4 * k + 2]);
                    acc0[4 * k + 3] = fmaf(w0, pv.w, acc0[4 * k + 3]);
                    acc1[4 * k + 0] = fmaf(w1, pv.x, acc1[4 * k + 0]);
                    acc1[4 * k + 1] = fmaf(w1, pv.y, acc1[4 * k + 1]);
                    acc1[4 * k + 2] = fmaf(w1, pv.z, acc1[4 * k + 2]);
                    acc1[4 * k + 3] = fmaf(w1, pv.w, acc1[4 * k + 3]);
                }
            }
        }
    }

    // ---- write partials ----
    const int q0g = qb0 + q0l, q1g = qb0 + q1l;
    if (g == 0) {
        mpart[chunk * BQ + q0g] = m0;  lpart[chunk * BQ + q0g] = l0;
        mpart[chunk * BQ + q1g] = m1;  lpart[chunk * BQ + q1g] = l1;
    }
    if (do_pv) {
        float* a0 = accp + ((size_t)chunk * BQ + q0g) * DD + 4 * g;
        float* a1 = accp + ((size_t)chunk * BQ + q1g) * DD + 4 * g;
#pragma unroll
        for (int k = 0; k < 8; ++k) {
            *reinterpret_cast<float4*>(a0 + 64 * k) =
                make_float4(acc0[4 * k], acc0[4 * k + 1], acc0[4 * k + 2], acc0[4 * k + 3]);
            *reinterpret_cast<float4*>(a1 + 64 * k) =
                make_float4(acc1[4 * k], acc1[4 * k + 1], acc1[4 * k + 2], acc1[4 * k + 3]);
        }
    }
}

// Combine the NCHK chunk partials per query: energy + next state.
__global__ __launch_bounds__(256) void hopf_combine(
    const float* __restrict__ state_cur,
    const float* __restrict__ mpart, const float* __restrict__ lpart,
    const float* __restrict__ accp,
    float* __restrict__ state_next, float* __restrict__ energy_out)
{
    const int lane = threadIdx.x & 63;
    const int w    = threadIdx.x >> 6;
    const int q    = blockIdx.x * 4 + w;

    float mv[NCHK];
    float M = -INFINITY;
#pragma unroll
    for (int c = 0; c < NCHK; ++c) {
        mv[c] = mpart[c * BQ + q];
        M = fmaxf(M, mv[c]);
    }
    float wx[NCHK];
    float L = 0.f;
#pragma unroll
    for (int c = 0; c < NCHK; ++c) {
        wx[c] = __expf(mv[c] - M);
        L += lpart[c * BQ + q] * wx[c];
    }

    // 0.5 * ||state||^2
    float ns = 0.f;
#pragma unroll
    for (int k = 0; k < 8; ++k) {
        const float v = state_cur[(size_t)q * DD + lane + 64 * k];
        ns = fmaf(v, v, ns);
    }
#pragma unroll
    for (int mk = 1; mk < 64; mk <<= 1) ns += __shfl_xor(ns, mk, 64);
    if (lane == 0) energy_out[q] = -(M + __logf(L)) + 0.5f * ns;   // beta = 1

    const float invL = 1.0f / L;
#pragma unroll
    for (int k = 0; k < 8; ++k) {
        const int d = lane + 64 * k;
        float a = 0.f;
#pragma unroll
        for (int c = 0; c < NCHK; ++c)
            a = fmaf(accp[((size_t)c * BQ + q) * DD + d], wx[c], a);
        state_next[(size_t)q * DD + d] = a * invL;
    }
}

extern "C" void kernel_launch(void* const* d_in, const int* in_sizes, int n_in,
                              void* d_out, int out_size, void* d_ws, size_t ws_size,
                              hipStream_t stream) {
    (void)in_sizes; (void)n_in; (void)out_size; (void)ws_size;
    const float* query    = (const float*)d_in[0];   // [1024, 512]
    const float* patterns = (const float*)d_in[1];   // [65536, 512]
    float* out = (float*)d_out;                      // state (524288) + energy (11*1024)

    float* stateA = (float*)d_ws;                    // B*D
    float* stateB = stateA + BQ * DD;                // B*D
    float* mpart  = stateB + BQ * DD;                // NCHK*B
    float* lpart  = mpart + NCHK * BQ;               // NCHK*B
    float* accp   = lpart + NCHK * BQ;               // NCHK*B*D (32 MB)

    hipMemcpyAsync(stateA, query, (size_t)BQ * DD * sizeof(float),
                   hipMemcpyDeviceToDevice, stream);

    float* energies = out + BQ * DD;
    const dim3 g1(NCHK, NQB);
    for (int t = 0; t <= NSTEP; ++t) {
        float* cur = (t & 1) ? stateB : stateA;
        float* nxt = (t & 1) ? stateA : stateB;
        hopf_pass<<<g1, 512, 0, stream>>>(patterns, cur, mpart, lpart, accp,
                                          (t < NSTEP) ? 1 : 0);
        hopf_combine<<<dim3(BQ / 4), 256, 0, stream>>>(cur, mpart, lpart, accp,
                                                       nxt, energies + t * BQ);
    }
    // state after step 9 (input of iteration 10) lives in stateA (10 is even)
    hipMemcpyAsync(out, stateA, (size_t)BQ * DD * sizeof(float),
                   hipMemcpyDeviceToDevice, stream);
}

// Round 2
// 3179.083 us; speedup vs baseline: 8.5735x; 8.5735x over previous
//
#include <hip/hip_runtime.h>
#include <hip/hip_bf16.h>
#include <stdint.h>
#include <math.h>

// Modern Hopfield retrieval, MFMA version.
// 11 passes: sims = state @ patterns^T (QK), online softmax, out = attn @ patterns (PV).
// B=1024, N=65536, D=512, beta=1.
//
// Pass kernel: grid (16 chunks x 16 q-blocks), 512 thr (8 waves), QB=64, NT=64.
//   QK:  sims^T[n][q] = mfma(A = pattern LDS tile rows, B = state frags in regs),
//        K=512 split in halves across wave pairs, partials merged through LDS.
//   SM:  per-q-column online softmax (col = lane&31 -> reg-max + shfl_xor(32)).
//   PV:  out^T[d][q] += mfma(A = patT frags from GLOBAL (L2-hot), B = Pr from LDS).
// Pattern tile double-buffered in LDS, reg-staged, XOR swizzle ^((row&7)<<4) bytes.

#define BQ    1024
#define DD    512
#define NP    65536
#define NSTEP 10
#define NCHK  16
#define CHK   4096        // NP/NCHK
#define QB    64
#define NQB   16
#define NT    64
#define NTILES 64         // CHK/NT

typedef __attribute__((ext_vector_type(8)))  short bfrag;   // 8 bf16 = 4 VGPR
typedef __attribute__((ext_vector_type(16))) float accf;    // 32x32 accumulator

__device__ __forceinline__ unsigned short f2bf(float f) {
    uint32_t u = __float_as_uint(f);
    u += 0x7FFFu + ((u >> 16) & 1u);   // RNE
    return (unsigned short)(u >> 16);
}

// ---------------- one-time converts ----------------

__global__ __launch_bounds__(256) void conv_patterns(
    const float* __restrict__ pat_f32,
    unsigned short* __restrict__ pat, unsigned short* __restrict__ patT)
{
    __shared__ unsigned short T[64][65];
    const int t  = threadIdx.x;
    const int n0 = (blockIdx.x >> 3) * 64, d0 = (blockIdx.x & 7) * 64;
    {
        const int r = t >> 2, c0 = (t & 3) * 16;
        const float* src = pat_f32 + (size_t)(n0 + r) * DD + d0 + c0;
        unsigned short loc[16];
#pragma unroll
        for (int j = 0; j < 16; ++j) loc[j] = f2bf(src[j]);
        unsigned short* d = pat + (size_t)(n0 + r) * DD + d0 + c0;
#pragma unroll
        for (int j = 0; j < 16; ++j) d[j] = loc[j];
#pragma unroll
        for (int j = 0; j < 16; ++j) T[r][c0 + j] = loc[j];
    }
    __syncthreads();
    {
        const int dl = t >> 2, nc0 = (t & 3) * 16;
        unsigned short* dst = patT + (size_t)(d0 + dl) * NP + n0 + nc0;
#pragma unroll
        for (int j = 0; j < 16; ++j) dst[j] = T[nc0 + j][dl];
    }
}

__global__ __launch_bounds__(256) void conv_state(
    const float* __restrict__ query, float* __restrict__ stA,
    unsigned short* __restrict__ stbf)
{
    const int stride = gridDim.x * 256;
    for (int k = blockIdx.x * 256 + threadIdx.x; k < BQ * DD; k += stride) {
        float v = query[k];
        stA[k] = v; stbf[k] = f2bf(v);
    }
}

// ---------------- main pass ----------------

__global__ __launch_bounds__(512, 2) void hopf_pass(
    const unsigned short* __restrict__ pat,    // [NP][DD] bf16
    const unsigned short* __restrict__ patT,   // [DD][NP] bf16
    const unsigned short* __restrict__ stbf,   // [BQ][DD] bf16
    float* __restrict__ mpart, float* __restrict__ lpart,
    float* __restrict__ accp,                  // [NCHK][DD][BQ] f32 (out^T partials)
    int do_pv)
{
    __shared__ unsigned short PatL[2][NT * DD];      // 2 x 64 KB, swizzled
    __shared__ float Sp[NT * 66];                    // K-half sims partials
    __shared__ unsigned short Pr[QB * 64];           // probs bf16, swizzled
    __shared__ float Marr[2 * QB];
    __shared__ float Sarr[2 * QB];
    __shared__ float Alr[QB];

    const int t  = threadIdx.x, ln = t & 63, w = t >> 6;
    const int lq = ln & 31, hi = ln >> 5;
    const int chunk = blockIdx.x, qb0 = blockIdx.y * QB;
    const int jn = w & 1, jq = (w >> 1) & 1, h = w >> 2;     // QK role
    const size_t nbase = (size_t)chunk * CHK;

    // state B-frags (regs): col q = qb0+jq*32+lq, k = h*256 + ks*16 + hi*8
    uint4 sfrag[16];
    {
        const unsigned short* sp = stbf + (size_t)(qb0 + jq * 32 + lq) * DD + h * 256 + hi * 8;
#pragma unroll
        for (int ks = 0; ks < 16; ++ks)
            sfrag[ks] = *reinterpret_cast<const uint4*>(sp + ks * 16);
    }

    accf acc[2][2];   // PV out^T: d rows = w*64 + dt*32, q cols = qt*32
#pragma unroll
    for (int a = 0; a < 2; ++a)
#pragma unroll
        for (int b = 0; b < 2; ++b)
#pragma unroll
            for (int i = 0; i < 16; ++i) acc[a][b][i] = 0.f;
    float m_run = -INFINITY, l_run = 0.f;

    // prologue: stage tile 0 into buf 0 (wave w stages rows w*8..w*8+7)
    {
#pragma unroll
        for (int i = 0; i < 8; ++i) {
            const int r = w * 8 + i;
            uint4 g = *reinterpret_cast<const uint4*>(pat + (nbase + r) * DD + ln * 8);
            *reinterpret_cast<uint4*>(&PatL[0][r * DD + ((ln * 8) ^ ((r & 7) << 3))]) = g;
        }
    }
    __syncthreads();

    for (int tile = 0; tile < NTILES; ++tile) {
        const int buf = tile & 1;
        const int ng  = tile * NT;

        // ---- QK: sims^T tile (jn,jq), K-half h ----
        accf sims;
#pragma unroll
        for (int i = 0; i < 16; ++i) sims[i] = 0.f;
        {
            const int n = jn * 32 + lq;
            const unsigned short* base = &PatL[buf][n * DD];
            const int boff = h * 256 + hi * 8;      // shorts within row
            const int sw   = (n & 7) << 3;          // swizzle (shorts)
#pragma unroll
            for (int ks = 0; ks < 16; ++ks) {
                bfrag a = *reinterpret_cast<const bfrag*>(base + ((boff + ks * 16) ^ sw));
                sims = __builtin_amdgcn_mfma_f32_32x32x16_bf16(
                    a, *reinterpret_cast<const bfrag*>(&sfrag[ks]), sims, 0, 0, 0);
            }
        }

        // ---- merge K-halves through LDS ----
        if (h == 1) {
#pragma unroll
            for (int i = 0; i < 16; ++i) {
                const int n = jn * 32 + (i & 3) + 8 * (i >> 2) + 4 * hi;
                Sp[n * 66 + jq * 32 + lq] = sims[i];
            }
        }
        __syncthreads();   // B1

        float alq = 0.f;
        if (h == 0) {
#pragma unroll
            for (int i = 0; i < 16; ++i) {
                const int n = jn * 32 + (i & 3) + 8 * (i >> 2) + 4 * hi;
                sims[i] += Sp[n * 66 + jq * 32 + lq];
            }
            float mx = sims[0];
#pragma unroll
            for (int i = 1; i < 16; ++i) mx = fmaxf(mx, sims[i]);
            mx = fmaxf(mx, __shfl_xor(mx, 32, 64));
            if (ln < 32) Marr[jn * QB + jq * 32 + lq] = mx;
        }
        __syncthreads();   // B2

        if (h == 0) {
            const int q = jq * 32 + lq;
            const float tm    = fmaxf(Marr[q], Marr[QB + q]);
            const float m_new = fmaxf(m_run, tm);
            alq = __expf(m_run - m_new);
            float p[16];
            float psum = 0.f;
#pragma unroll
            for (int i = 0; i < 16; ++i) { p[i] = __expf(sims[i] - m_new); psum += p[i]; }
            psum += __shfl_xor(psum, 32, 64);
            if (ln < 32) {
                Sarr[jn * QB + q] = psum;
                if (jn == 0) Alr[q] = alq;
            }
            if (do_pv) {
#pragma unroll
                for (int r = 0; r < 4; ++r) {
                    ushort4 pk;
                    pk.x = f2bf(p[4 * r + 0]); pk.y = f2bf(p[4 * r + 1]);
                    pk.z = f2bf(p[4 * r + 2]); pk.w = f2bf(p[4 * r + 3]);
                    const int n0  = jn * 32 + 8 * r + 4 * hi;
                    const int off = (q * 64 + n0) ^ ((q & 7) << 3);
                    *reinterpret_cast<ushort4*>(&Pr[off]) = pk;
                }
            }
            m_run = m_new;
        }
        __syncthreads();   // B3: Pr/Alr/Sarr visible

        if (h == 0) {
            const int q = jq * 32 + lq;
            l_run = l_run * alq + Sarr[q] + Sarr[QB + q];
        }

        // ---- issue staging loads for next tile (reg round-trip) ----
        uint4 sg[8];
        if (tile + 1 < NTILES) {
#pragma unroll
            for (int i = 0; i < 8; ++i)
                sg[i] = *reinterpret_cast<const uint4*>(
                    pat + (nbase + (size_t)(tile + 1) * NT + w * 8 + i) * DD + ln * 8);
        }

        // ---- PV: out^T += patT-frag @ Pr ----
        if (do_pv) {
            const float a0 = Alr[lq], a1 = Alr[32 + lq];
#pragma unroll
            for (int dt = 0; dt < 2; ++dt)
#pragma unroll
                for (int i = 0; i < 16; ++i) { acc[dt][0][i] *= a0; acc[dt][1][i] *= a1; }

            const size_t d0 = (size_t)(w * 64 + lq);
            const int swp = (lq & 7) << 3;
#pragma unroll
            for (int ks = 0; ks < 4; ++ks) {
                const size_t ncol = nbase + ng + ks * 16 + hi * 8;
                uint4 ga0 = *reinterpret_cast<const uint4*>(patT + d0 * NP + ncol);
                uint4 ga1 = *reinterpret_cast<const uint4*>(patT + (d0 + 32) * NP + ncol);
                const int o0 = ((lq) * 64 + ks * 16 + hi * 8) ^ swp;
                const int o1 = ((32 + lq) * 64 + ks * 16 + hi * 8) ^ swp;
                bfrag b0 = *reinterpret_cast<const bfrag*>(&Pr[o0]);
                bfrag b1 = *reinterpret_cast<const bfrag*>(&Pr[o1]);
                acc[0][0] = __builtin_amdgcn_mfma_f32_32x32x16_bf16(*(const bfrag*)&ga0, b0, acc[0][0], 0, 0, 0);
                acc[0][1] = __builtin_amdgcn_mfma_f32_32x32x16_bf16(*(const bfrag*)&ga0, b1, acc[0][1], 0, 0, 0);
                acc[1][0] = __builtin_amdgcn_mfma_f32_32x32x16_bf16(*(const bfrag*)&ga1, b0, acc[1][0], 0, 0, 0);
                acc[1][1] = __builtin_amdgcn_mfma_f32_32x32x16_bf16(*(const bfrag*)&ga1, b1, acc[1][1], 0, 0, 0);
            }
        }

        // ---- write staged regs into other LDS buffer ----
        if (tile + 1 < NTILES) {
#pragma unroll
            for (int i = 0; i < 8; ++i) {
                const int r = w * 8 + i;
                *reinterpret_cast<uint4*>(&PatL[buf ^ 1][r * DD + ((ln * 8) ^ ((r & 7) << 3))]) = sg[i];
            }
        }
        __syncthreads();   // B0: next tile staged, Sp/Pr reusable
    }

    // ---- partials out ----
    if (h == 0 && jn == 0 && ln < 32) {
        const int q = qb0 + jq * 32 + lq;
        mpart[chunk * BQ + q] = m_run;
        lpart[chunk * BQ + q] = l_run;
    }
    if (do_pv) {
        float* ap = accp + (size_t)chunk * DD * BQ;
#pragma unroll
        for (int dt = 0; dt < 2; ++dt)
#pragma unroll
            for (int qt = 0; qt < 2; ++qt)
#pragma unroll
                for (int i = 0; i < 16; ++i) {
                    const int dr = w * 64 + dt * 32 + (i & 3) + 8 * (i >> 2) + 4 * hi;
                    ap[(size_t)dr * BQ + qb0 + qt * 32 + lq] = acc[dt][qt][i];
                }
    }
}

// ---------------- combine: merge chunk partials -> next state ----------------

__global__ __launch_bounds__(256) void hopf_combine(
    const float* __restrict__ mpart, const float* __restrict__ lpart,
    const float* __restrict__ accp,
    float* __restrict__ state_next, unsigned short* __restrict__ stbf_next)
{
    __shared__ float T[64][69];
    const int t  = threadIdx.x;
    const int qb = blockIdx.x, db = blockIdx.y;   // (16, 8)
    const int q  = qb * 64 + (t & 63);
    const int dg = t >> 6;                         // 0..3

    float mv[NCHK];
    float M = -INFINITY;
#pragma unroll
    for (int c = 0; c < NCHK; ++c) { mv[c] = mpart[c * BQ + q]; M = fmaxf(M, mv[c]); }
    float wx[NCHK];
    float L = 0.f;
#pragma unroll
    for (int c = 0; c < NCHK; ++c) { wx[c] = __expf(mv[c] - M); L += lpart[c * BQ + q] * wx[c]; }
    const float invL = 1.f / L;

    float v[16];
#pragma unroll
    for (int k = 0; k < 16; ++k) v[k] = 0.f;
    for (int c = 0; c < NCHK; ++c) {
        const float* ap = accp + ((size_t)c * DD + db * 64 + dg) * BQ + q;
#pragma unroll
        for (int k = 0; k < 16; ++k) v[k] = fmaf(wx[c], ap[(size_t)(4 * k) * BQ], v[k]);
    }
#pragma unroll
    for (int k = 0; k < 16; ++k) T[t & 63][dg + 4 * k] = v[k] * invL;
    __syncthreads();
    {
        const int qo = t >> 2, ds = (t & 3) * 16;
        float o[16];
#pragma unroll
        for (int j = 0; j < 16; ++j) o[j] = T[qo][ds + j];
        float* dst = state_next + (size_t)(qb * 64 + qo) * DD + db * 64 + ds;
        unsigned short* bdst = stbf_next + (size_t)(qb * 64 + qo) * DD + db * 64 + ds;
#pragma unroll
        for (int j = 0; j < 16; ++j) dst[j] = o[j];
#pragma unroll
        for (int j = 0; j < 16; ++j) bdst[j] = f2bf(o[j]);
    }
}

// ---------------- energy ----------------

__global__ __launch_bounds__(256) void hopf_energy(
    const float* __restrict__ state_cur,
    const float* __restrict__ mpart, const float* __restrict__ lpart,
    float* __restrict__ eout)
{
    const int ln = threadIdx.x & 63, w = threadIdx.x >> 6;
    const int q  = blockIdx.x * 4 + w;
    float mv[NCHK];
    float M = -INFINITY;
#pragma unroll
    for (int c = 0; c < NCHK; ++c) { mv[c] = mpart[c * BQ + q]; M = fmaxf(M, mv[c]); }
    float L = 0.f;
#pragma unroll
    for (int c = 0; c < NCHK; ++c) L += lpart[c * BQ + q] * __expf(mv[c] - M);
    float ns = 0.f;
#pragma unroll
    for (int k = 0; k < 8; ++k) {
        const float vv = state_cur[(size_t)q * DD + ln + 64 * k];
        ns = fmaf(vv, vv, ns);
    }
#pragma unroll
    for (int mk = 1; mk < 64; mk <<= 1) ns += __shfl_xor(ns, mk, 64);
    if (ln == 0) eout[q] = -(M + __logf(L)) + 0.5f * ns;   // beta = 1
}

// ---------------- launch ----------------

extern "C" void kernel_launch(void* const* d_in, const int* in_sizes, int n_in,
                              void* d_out, int out_size, void* d_ws, size_t ws_size,
                              hipStream_t stream) {
    (void)in_sizes; (void)n_in; (void)out_size; (void)ws_size;
    const float* query    = (const float*)d_in[0];   // [1024, 512]
    const float* patterns = (const float*)d_in[1];   // [65536, 512]
    float* out = (float*)d_out;

    uint8_t* ws = (uint8_t*)d_ws;
    unsigned short* pat  = (unsigned short*)ws; ws += (size_t)NP * DD * 2;   // 67 MB
    unsigned short* patT = (unsigned short*)ws; ws += (size_t)NP * DD * 2;   // 67 MB
    float* stateA = (float*)ws; ws += (size_t)BQ * DD * 4;
    float* stateB = (float*)ws; ws += (size_t)BQ * DD * 4;
    unsigned short* stbf = (unsigned short*)ws; ws += (size_t)BQ * DD * 2;
    float* mpart = (float*)ws; ws += (size_t)NCHK * BQ * 4;
    float* lpart = (float*)ws; ws += (size_t)NCHK * BQ * 4;
    float* accp  = (float*)ws; ws += (size_t)NCHK * DD * BQ * 4;             // 32 MB

    conv_patterns<<<dim3(8192), 256, 0, stream>>>(patterns, pat, patT);
    conv_state<<<dim3(512), 256, 0, stream>>>(query, stateA, stbf);

    float* energies = out + BQ * DD;
    for (int t = 0; t <= NSTEP; ++t) {
        float* cur = (t & 1) ? stateB : stateA;
        float* nxt = (t & 1) ? stateA : stateB;
        hopf_pass<<<dim3(NCHK, NQB), 512, 0, stream>>>(pat, patT, stbf, mpart, lpart,
                                                       accp, (t < NSTEP) ? 1 : 0);
        hopf_energy<<<dim3(BQ / 4), 256, 0, stream>>>(cur, mpart, lpart, energies + t * BQ);
        if (t < NSTEP)
            hopf_combine<<<dim3(NQB, 8), 256, 0, stream>>>(mpart, lpart, accp, nxt, stbf);
    }
    hipMemcpyAsync(out, stateA, (size_t)BQ * DD * 4, hipMemcpyDeviceToDevice, stream);
}